// Round 3
// baseline (531.178 us; speedup 1.0000x reference)
//
#include <hip/hip_runtime.h>

#define B_   64
#define T_   2048
#define TM1  2047
#define D_   64
#define M_FULL (B_ * TM1)        // 131008

#define PID(i,j) ((i)*((i)-1)/2 + (j))

typedef __attribute__((ext_vector_type(8))) short bf16x8;
typedef __attribute__((ext_vector_type(4))) float f32x4;

__device__ __forceinline__ unsigned f2bf(float v) {
    unsigned u = __float_as_uint(v);
    u = (u + 0x7FFFu + ((u >> 16) & 1u)) >> 16;   // RNE
    return u;
}

// ---------------- K1: dX -> Mlie -> expm(s=3, Horner-9) -> LN -> fws bf16 (pos-major [M][256])
__global__ __launch_bounds__(256, 4) void k_expm_f(
    const float* __restrict__ x, const float* __restrict__ mask,
    const float* __restrict__ Wd, const float* __restrict__ lng,
    const float* __restrict__ lnb, unsigned short* __restrict__ fws,
    int b0)
{
    __shared__ __align__(16) float xT[64 * 65];   // 16.64 KB only
    const int tid  = threadIdx.x;
    const int lane = tid & 63;
    const int wq   = __builtin_amdgcn_readfirstlane(tid >> 6);
    const int bl   = blockIdx.x >> 5;             // local b
    const int b    = b0 + bl;
    const int t0   = (blockIdx.x & 31) << 6;

    const float* xb = x + (size_t)b * (T_ * D_);
    for (int idx = tid; idx < 65 * 64; idx += 256) {
        int r = idx >> 6, c = idx & 63;
        int tr = t0 + r;
        xT[c * 65 + r] = (tr < T_) ? xb[tr * 64 + c] : 0.f;
    }
    __syncthreads();

    const int t = t0 + lane;
    const bool valid = (t < TM1);
    const float mk = valid ? mask[b * T_ + t + 1] : 0.f;

    float al[28];
    #pragma unroll
    for (int p = 0; p < 28; ++p) al[p] = 0.f;
    const float* Wg = Wd + wq * (16 * 64);
    #pragma unroll
    for (int d = 0; d < 16; ++d) {
        const float* col = &xT[(wq * 16 + d) * 65 + lane];
        float dxd = (col[1] - col[0]) * mk;
        const float* Wrow = Wg + d * 64;
        #pragma unroll
        for (int i = 1; i < 8; ++i)
            #pragma unroll
            for (int j = 0; j < i; ++j)
                al[PID(i, j)] = fmaf(dxd, Wrow[i * 8 + j], al[PID(i, j)]);
    }

    #pragma unroll
    for (int p = 0; p < 28; ++p) al[p] *= 0.125f;

    float R[64];
    #pragma unroll
    for (int i = 0; i < 8; ++i)
        #pragma unroll
        for (int j = 0; j < 8; ++j)
            R[i * 8 + j] = (i == j) ? 1.f : 0.f;

    for (int k = 9; k >= 1; --k) {
        float invk = 1.f / (float)k;
        #pragma unroll
        for (int j = 0; j < 8; ++j) {
            float tmp[8];
            #pragma unroll
            for (int i = 0; i < 8; ++i) tmp[i] = R[i * 8 + j];
            #pragma unroll
            for (int i = 0; i < 8; ++i) {
                float s = 0.f;
                #pragma unroll
                for (int kk = 0; kk < 8; ++kk) {
                    if (kk == i) continue;
                    float a = (i > kk) ? al[PID(i, kk)] : -al[PID(kk, i)];
                    s = fmaf(a, tmp[kk], s);
                }
                R[i * 8 + j] = ((i == j) ? 1.f : 0.f) + invk * s;
            }
        }
    }
    for (int sq = 0; sq < 3; ++sq) {
        float nw[64];
        #pragma unroll
        for (int i = 0; i < 8; ++i)
            #pragma unroll
            for (int j = 0; j < 8; ++j) {
                float s = 0.f;
                #pragma unroll
                for (int kk = 0; kk < 8; ++kk)
                    s = fmaf(R[i * 8 + kk], R[kk * 8 + j], s);
                nw[i * 8 + j] = s;
            }
        #pragma unroll
        for (int e = 0; e < 64; ++e) R[e] = nw[e];
    }

    float sum = 0.f, ssq = 0.f;
    #pragma unroll
    for (int e = 0; e < 64; ++e) { sum += R[e]; ssq = fmaf(R[e], R[e], ssq); }
    float mu   = sum * (1.f / 64.f);
    float var  = ssq * (1.f / 64.f) - mu * mu;
    float rstd = rsqrtf(var + 1e-5f);

    if (valid) {
        size_t lpos = (size_t)bl * TM1 + t;
        unsigned short* dst = fws + lpos * 256 + wq * 64;
        #pragma unroll
        for (int eq = 0; eq < 8; ++eq) {
            unsigned u[4];
            #pragma unroll
            for (int p = 0; p < 4; ++p) {
                int e = eq * 8 + p * 2;
                float v0 = fmaf((R[e]   - mu) * rstd, lng[e],   lnb[e]);
                float v1 = fmaf((R[e+1] - mu) * rstd, lng[e+1], lnb[e+1]);
                u[p] = f2bf(v0) | (f2bf(v1) << 16);
            }
            uint4 pk = make_uint4(u[0], u[1], u[2], u[3]);
            *(uint4*)(dst + eq * 8) = pk;
        }
    }
}

// ---------------- K2: MFMA GEMM  f_proj[pos][o] = fws[pos][:] @ pw + pb
__global__ __launch_bounds__(256, 4) void k_gemm(
    const unsigned short* __restrict__ fws, const float* __restrict__ pw,
    const float* __restrict__ pb, float* __restrict__ f_proj,
    int M_len, int pos_off)
{
    __shared__ __align__(16) char Ash[64 * 128 * 2];   // [row64][k128] bf16, XOR-swizzled
    __shared__ __align__(16) char Bsh[64 * 128 * 2];   // [o64][k128]  bf16, XOR-swizzled
    const int tid = threadIdx.x;
    const int l   = tid & 63;
    const int w   = tid >> 6;
    const int m0  = blockIdx.x * 64;

    f32x4 acc[4];
    #pragma unroll
    for (int nt = 0; nt < 4; ++nt) acc[nt] = (f32x4)(0.f);

    for (int kc = 0; kc < 2; ++kc) {
        __syncthreads();
        // stage A tile: 64 rows x 128 k (256B/row) via float4
        for (int i = tid; i < 1024; i += 256) {
            int row = i >> 4, q = i & 15;
            int dstoff = (row * 256 + q * 16) ^ ((row & 7) << 4);
            float4 v = make_float4(0.f, 0.f, 0.f, 0.f);
            if (m0 + row < M_len)
                v = *(const float4*)(fws + (size_t)(m0 + row) * 256 + kc * 128 + q * 8);
            *(float4*)(Ash + dstoff) = v;
        }
        // stage B transposed: Bsh[o][k] from pw fp32 (k,o)
        for (int i = tid; i < 4096; i += 256) {
            int o = i >> 6, kp = i & 63;
            int k = kc * 128 + kp * 2;
            unsigned u0 = f2bf(pw[(size_t)k * 64 + o]);
            unsigned u1 = f2bf(pw[(size_t)(k + 1) * 64 + o]);
            int dstoff = (o * 256 + kp * 4) ^ ((o & 7) << 4);
            *(unsigned*)(Bsh + dstoff) = u0 | (u1 << 16);
        }
        __syncthreads();
        #pragma unroll
        for (int ks = 0; ks < 4; ++ks) {
            int arow = w * 16 + (l & 15);
            int aoff = (arow * 256 + ks * 64 + ((l >> 4) << 4)) ^ ((arow & 7) << 4);
            bf16x8 a = *(const bf16x8*)(Ash + aoff);
            #pragma unroll
            for (int nt = 0; nt < 4; ++nt) {
                int orow = nt * 16 + (l & 15);
                int boff = (orow * 256 + ks * 64 + ((l >> 4) << 4)) ^ ((orow & 7) << 4);
                bf16x8 bb = *(const bf16x8*)(Bsh + boff);
                acc[nt] = __builtin_amdgcn_mfma_f32_16x16x32_bf16(a, bb, acc[nt], 0, 0, 0);
            }
        }
    }
    #pragma unroll
    for (int nt = 0; nt < 4; ++nt) {
        int col = nt * 16 + (l & 15);
        float bias = pb[col];
        #pragma unroll
        for (int r = 0; r < 4; ++r) {
            int row = w * 16 + (l >> 4) * 4 + r;
            if (m0 + row < M_len)
                f_proj[(size_t)(pos_off + m0 + row) * 64 + col] = acc[nt][r] + bias;
        }
    }
}

// ---------------- fallback (R2-proven): full fused kernel writing f_proj
__global__ __launch_bounds__(256, 3) void k_expm_fb(
    const float* __restrict__ x, const float* __restrict__ mask,
    const float* __restrict__ Wd, const float* __restrict__ lng,
    const float* __restrict__ lnb, const float* __restrict__ pw,
    const float* __restrict__ pb, float* __restrict__ f_out)
{
    __shared__ __align__(16) unsigned char smA[256 * 64 * 2];
    __shared__ __align__(16) float pwsh[64 * 64];
    float* xT = (float*)smA;
    unsigned short* fsh = (unsigned short*)smA;

    const int tid  = threadIdx.x;
    const int lane = tid & 63;
    const int wq   = __builtin_amdgcn_readfirstlane(tid >> 6);
    const int b    = blockIdx.x >> 5;
    const int t0   = (blockIdx.x & 31) << 6;

    const float* xb = x + (size_t)b * (T_ * D_);
    for (int idx = tid; idx < 65 * 64; idx += 256) {
        int r = idx >> 6, c = idx & 63;
        int tr = t0 + r;
        xT[c * 65 + r] = (tr < T_) ? xb[tr * 64 + c] : 0.f;
    }
    __syncthreads();

    const int t = t0 + lane;
    const bool valid = (t < TM1);
    const float mk = valid ? mask[b * T_ + t + 1] : 0.f;

    float al[28];
    #pragma unroll
    for (int p = 0; p < 28; ++p) al[p] = 0.f;
    const float* Wg = Wd + wq * (16 * 64);
    #pragma unroll
    for (int d = 0; d < 16; ++d) {
        const float* col = &xT[(wq * 16 + d) * 65 + lane];
        float dxd = (col[1] - col[0]) * mk;
        const float* Wrow = Wg + d * 64;
        #pragma unroll
        for (int i = 1; i < 8; ++i)
            #pragma unroll
            for (int j = 0; j < i; ++j)
                al[PID(i, j)] = fmaf(dxd, Wrow[i * 8 + j], al[PID(i, j)]);
    }
    __syncthreads();

    #pragma unroll
    for (int p = 0; p < 28; ++p) al[p] *= 0.125f;

    float R[64];
    #pragma unroll
    for (int i = 0; i < 8; ++i)
        #pragma unroll
        for (int j = 0; j < 8; ++j)
            R[i * 8 + j] = (i == j) ? 1.f : 0.f;
    for (int k = 9; k >= 1; --k) {
        float invk = 1.f / (float)k;
        #pragma unroll
        for (int j = 0; j < 8; ++j) {
            float tmp[8];
            #pragma unroll
            for (int i = 0; i < 8; ++i) tmp[i] = R[i * 8 + j];
            #pragma unroll
            for (int i = 0; i < 8; ++i) {
                float s = 0.f;
                #pragma unroll
                for (int kk = 0; kk < 8; ++kk) {
                    if (kk == i) continue;
                    float a = (i > kk) ? al[PID(i, kk)] : -al[PID(kk, i)];
                    s = fmaf(a, tmp[kk], s);
                }
                R[i * 8 + j] = ((i == j) ? 1.f : 0.f) + invk * s;
            }
        }
    }
    for (int sq = 0; sq < 3; ++sq) {
        float nw[64];
        #pragma unroll
        for (int i = 0; i < 8; ++i)
            #pragma unroll
            for (int j = 0; j < 8; ++j) {
                float s = 0.f;
                #pragma unroll
                for (int kk = 0; kk < 8; ++kk)
                    s = fmaf(R[i * 8 + kk], R[kk * 8 + j], s);
                nw[i * 8 + j] = s;
            }
        #pragma unroll
        for (int e = 0; e < 64; ++e) R[e] = nw[e];
    }

    float sum = 0.f, ssq = 0.f;
    #pragma unroll
    for (int e = 0; e < 64; ++e) { sum += R[e]; ssq = fmaf(R[e], R[e], ssq); }
    float mu   = sum * (1.f / 64.f);
    float var  = ssq * (1.f / 64.f) - mu * mu;
    float rstd = rsqrtf(var + 1e-5f);

    #pragma unroll
    for (int e = 0; e < 64; ++e) {
        float nv = fmaf((R[e] - mu) * rstd, lng[e], lnb[e]);
        fsh[(wq * 64 + e) * 64 + lane] = (unsigned short)f2bf(nv);
    }

    float acc[16];
    #pragma unroll
    for (int j = 0; j < 16; ++j) acc[j] = 0.f;
    for (int c = 0; c < 4; ++c) {
        __syncthreads();
        for (int idx = tid; idx < 4096; idx += 256)
            pwsh[idx] = pw[c * 4096 + idx];
        __syncthreads();
        #pragma unroll 4
        for (int e = 0; e < 64; ++e) {
            float fe = __uint_as_float((unsigned)fsh[(c * 64 + e) * 64 + lane] << 16);
            const float* wr = &pwsh[e * 64 + wq * 16];
            #pragma unroll
            for (int j = 0; j < 16; ++j)
                acc[j] = fmaf(fe, wr[j], acc[j]);
        }
    }
    if (valid) {
        float* dst = f_out + ((size_t)b * TM1 + t) * 64 + wq * 16;
        #pragma unroll
        for (int j = 0; j < 16; ++j) dst[j] = acc[j] + pb[wq * 16 + j];
    }
}

// ---------------- K3: pooled / denom
__global__ void k_pool(const float* __restrict__ x, const float* __restrict__ mask,
                       const float* __restrict__ f, float* __restrict__ pooled,
                       float* __restrict__ denom)
{
    const int b  = blockIdx.x >> 5;
    const int t0 = (blockIdx.x & 31) << 6;
    const int o  = threadIdx.x & 63;
    const int tr = threadIdx.x >> 6;
    const float* xb = x + (size_t)b * (T_ * D_);
    const float* fb = f + (size_t)b * (TM1 * 64);
    float acc = 0.f, am = 0.f;
    #pragma unroll 4
    for (int i = 0; i < 16; ++i) {
        int tt = t0 + i * 4 + tr;
        float mk  = mask[b * T_ + tt];
        float pos = fminf(fmaxf((tt + 0.5f) * (2047.f / 2048.f) - 0.5f, 0.f), 2046.f);
        int   i0  = (int)pos;
        float w   = pos - (float)i0;
        int   i1  = min(i0 + 1, 2046);
        float fi  = fb[i0 * 64 + o] * (1.f - w) + fb[i1 * 64 + o] * w;
        float h1  = xb[tt * 64 + o] + fi;
        acc = fmaf(h1, mk, acc);
        am += mk;
    }
    atomicAdd(&pooled[b * 64 + o], acc);
    if (o == 0) atomicAdd(&denom[b], am);
}

// ---------------- K4: SE gate
__global__ void k_se(const float* __restrict__ pooled, const float* __restrict__ denom,
                     const float* __restrict__ w1, const float* __restrict__ b1,
                     const float* __restrict__ w2, const float* __restrict__ b2,
                     float* __restrict__ s_out)
{
    __shared__ float pl[64];
    __shared__ float hid[4];
    const int b = blockIdx.x, o = threadIdx.x;
    float p = pooled[b * 64 + o] / denom[b];
    pl[o] = p;
    __syncthreads();
    if (o < 4) {
        float h = b1[o];
        for (int e = 0; e < 64; ++e) h = fmaf(pl[e], w1[e * 4 + o], h);
        hid[o] = 0.5f * h * (1.f + erff(h * 0.70710678118654752f));
    }
    __syncthreads();
    float sv = b2[o];
    #pragma unroll
    for (int hh = 0; hh < 4; ++hh) sv = fmaf(hid[hh], w2[hh * 64 + o], sv);
    s_out[b * 64 + o] = 1.f / (1.f + expf(-sv));
}

// ---------------- K5: out = (x + interp(f)) * s + x
__global__ void k_apply(const float* __restrict__ x, const float* __restrict__ f,
                        const float* __restrict__ s, float* __restrict__ out)
{
    int gid = blockIdx.x * 256 + threadIdx.x;
    int o = gid & 63;
    int t = (gid >> 6) & 2047;
    int b = gid >> 17;
    float pos = fminf(fmaxf((t + 0.5f) * (2047.f / 2048.f) - 0.5f, 0.f), 2046.f);
    int   i0  = (int)pos;
    float w   = pos - (float)i0;
    int   i1  = min(i0 + 1, 2046);
    const float* fb = f + (size_t)b * (TM1 * 64);
    float fi = fb[i0 * 64 + o] * (1.f - w) + fb[i1 * 64 + o] * w;
    float xv = x[gid];
    float h1 = xv + fi;
    out[gid] = fmaf(h1, s[b * 64 + o], xv);
}

extern "C" void kernel_launch(void* const* d_in, const int* in_sizes, int n_in,
                              void* d_out, int out_size, void* d_ws, size_t ws_size,
                              hipStream_t stream)
{
    const float* x    = (const float*)d_in[0];
    const float* mask = (const float*)d_in[1];
    const float* Wd   = (const float*)d_in[2];
    const float* lng  = (const float*)d_in[3];
    const float* lnb  = (const float*)d_in[4];
    const float* pw   = (const float*)d_in[5];
    const float* pb   = (const float*)d_in[6];
    const float* sw1  = (const float*)d_in[7];
    const float* sb1  = (const float*)d_in[8];
    const float* sw2  = (const float*)d_in[9];
    const float* sb2  = (const float*)d_in[10];

    float* out    = (float*)d_out;
    float* pooled = (float*)d_ws;                   // 4096
    float* denom  = pooled + 4096;                  // 64
    float* s_ws   = denom + 64;                     // 4096
    float* f_proj = s_ws + 4096;                    // 8,384,512 floats (33.5 MB)
    unsigned short* fws = (unsigned short*)(f_proj + (size_t)M_FULL * 64);

    const size_t base_bytes = (size_t)(4096 + 64 + 4096 + (size_t)M_FULL * 64) * 4;
    const size_t need_full  = base_bytes + (size_t)M_FULL * 256 * 2;         // +67.1 MB
    const size_t need_half  = base_bytes + (size_t)(M_FULL / 2) * 256 * 2;   // +33.5 MB

    hipMemsetAsync(pooled, 0, (4096 + 64) * sizeof(float), stream);

    if (ws_size >= need_full) {
        hipLaunchKernelGGL(k_expm_f, dim3(2048), dim3(256), 0, stream,
                           x, mask, Wd, lng, lnb, fws, 0);
        hipLaunchKernelGGL(k_gemm, dim3(M_FULL / 64), dim3(256), 0, stream,
                           fws, pw, pb, f_proj, M_FULL, 0);
    } else if (ws_size >= need_half) {
        const int Mh = M_FULL / 2;                  // 65504 = 32*2047
        hipLaunchKernelGGL(k_expm_f, dim3(1024), dim3(256), 0, stream,
                           x, mask, Wd, lng, lnb, fws, 0);
        hipLaunchKernelGGL(k_gemm, dim3((Mh + 63) / 64), dim3(256), 0, stream,
                           fws, pw, pb, f_proj, Mh, 0);
        hipLaunchKernelGGL(k_expm_f, dim3(1024), dim3(256), 0, stream,
                           x, mask, Wd, lng, lnb, fws, 32);
        hipLaunchKernelGGL(k_gemm, dim3((Mh + 63) / 64), dim3(256), 0, stream,
                           fws, pw, pb, f_proj, Mh, Mh);
    } else {
        hipLaunchKernelGGL(k_expm_fb, dim3(2048), dim3(256), 0, stream,
                           x, mask, Wd, lng, lnb, pw, pb, f_proj);
    }

    hipLaunchKernelGGL(k_pool, dim3(2048), dim3(256), 0, stream,
                       x, mask, f_proj, pooled, denom);
    hipLaunchKernelGGL(k_se, dim3(64), dim3(64), 0, stream,
                       pooled, denom, sw1, sb1, sw2, sb2, s_ws);
    hipLaunchKernelGGL(k_apply, dim3(32768), dim3(256), 0, stream,
                       x, f_proj, s_ws, out);

    hipMemcpyAsync(out + (size_t)B_ * T_ * D_, mask,
                   (size_t)B_ * T_ * sizeof(float), hipMemcpyDeviceToDevice, stream);
}

// Round 5
// 312.449 us; speedup vs baseline: 1.7001x; 1.7001x over previous
//
#include <hip/hip_runtime.h>

#define B_   64
#define T_   2048
#define TM1  2047
#define D_   64
#define M_FULL (B_ * TM1)        // 131008

#define PID(i,j) ((i)*((i)-1)/2 + (j))

typedef __attribute__((ext_vector_type(8))) short bf16x8;
typedef __attribute__((ext_vector_type(4))) float f32x4;

__device__ __forceinline__ unsigned f2bf(float v) {
    unsigned u = __float_as_uint(v);
    u = (u + 0x7FFFu + ((u >> 16) & 1u)) >> 16;   // RNE
    return u;
}

// ---------------- K1: dX -> Mlie -> expm(s=3, Horner-9) -> LN -> fws bf16 (pos-major [M][256])
// launch_bounds(256,3): unified VGPR+AGPR budget ~170/wave -- the expm live set
// spills to AGPRs (traffic-free). (256,4) caps at 128 and spills to scratch (R3: 1GB traffic).
__global__ __launch_bounds__(256, 3) void k_expm_f(
    const float* __restrict__ x, const float* __restrict__ mask,
    const float* __restrict__ Wd, const float* __restrict__ lng,
    const float* __restrict__ lnb, unsigned short* __restrict__ fws,
    int b0)
{
    __shared__ __align__(16) float xT[64 * 65];   // 16.64 KB
    const int tid  = threadIdx.x;
    const int lane = tid & 63;
    const int wq   = __builtin_amdgcn_readfirstlane(tid >> 6);
    const int bl   = blockIdx.x >> 5;
    const int b    = b0 + bl;
    const int t0   = (blockIdx.x & 31) << 6;

    const float* xb = x + (size_t)b * (T_ * D_);
    for (int idx = tid; idx < 65 * 64; idx += 256) {
        int r = idx >> 6, c = idx & 63;
        int tr = t0 + r;
        xT[c * 65 + r] = (tr < T_) ? xb[tr * 64 + c] : 0.f;
    }
    __syncthreads();

    const int t = t0 + lane;
    const bool valid = (t < TM1);
    const float mk = valid ? mask[b * T_ + t + 1] : 0.f;

    float al[28];
    #pragma unroll
    for (int p = 0; p < 28; ++p) al[p] = 0.f;
    const float* Wg = Wd + wq * (16 * 64);
    #pragma unroll
    for (int d = 0; d < 16; ++d) {
        const float* col = &xT[(wq * 16 + d) * 65 + lane];
        float dxd = (col[1] - col[0]) * mk;
        const float* Wrow = Wg + d * 64;
        #pragma unroll
        for (int i = 1; i < 8; ++i)
            #pragma unroll
            for (int j = 0; j < i; ++j)
                al[PID(i, j)] = fmaf(dxd, Wrow[i * 8 + j], al[PID(i, j)]);
    }

    #pragma unroll
    for (int p = 0; p < 28; ++p) al[p] *= 0.125f;

    float R[64];
    #pragma unroll
    for (int i = 0; i < 8; ++i)
        #pragma unroll
        for (int j = 0; j < 8; ++j)
            R[i * 8 + j] = (i == j) ? 1.f : 0.f;

    for (int k = 9; k >= 1; --k) {
        float invk = 1.f / (float)k;
        #pragma unroll
        for (int j = 0; j < 8; ++j) {
            float tmp[8];
            #pragma unroll
            for (int i = 0; i < 8; ++i) tmp[i] = R[i * 8 + j];
            #pragma unroll
            for (int i = 0; i < 8; ++i) {
                float s = 0.f;
                #pragma unroll
                for (int kk = 0; kk < 8; ++kk) {
                    if (kk == i) continue;
                    float a = (i > kk) ? al[PID(i, kk)] : -al[PID(kk, i)];
                    s = fmaf(a, tmp[kk], s);
                }
                R[i * 8 + j] = ((i == j) ? 1.f : 0.f) + invk * s;
            }
        }
    }
    for (int sq = 0; sq < 3; ++sq) {
        float nw[64];
        #pragma unroll
        for (int i = 0; i < 8; ++i)
            #pragma unroll
            for (int j = 0; j < 8; ++j) {
                float s = 0.f;
                #pragma unroll
                for (int kk = 0; kk < 8; ++kk)
                    s = fmaf(R[i * 8 + kk], R[kk * 8 + j], s);
                nw[i * 8 + j] = s;
            }
        #pragma unroll
        for (int e = 0; e < 64; ++e) R[e] = nw[e];
    }

    float sum = 0.f, ssq = 0.f;
    #pragma unroll
    for (int e = 0; e < 64; ++e) { sum += R[e]; ssq = fmaf(R[e], R[e], ssq); }
    float mu   = sum * (1.f / 64.f);
    float var  = ssq * (1.f / 64.f) - mu * mu;
    float rstd = rsqrtf(var + 1e-5f);

    if (valid) {
        size_t lpos = (size_t)bl * TM1 + t;
        unsigned short* dst = fws + lpos * 256 + wq * 64;
        #pragma unroll
        for (int eq = 0; eq < 8; ++eq) {
            unsigned u[4];
            #pragma unroll
            for (int p = 0; p < 4; ++p) {
                int e = eq * 8 + p * 2;
                float v0 = fmaf((R[e]   - mu) * rstd, lng[e],   lnb[e]);
                float v1 = fmaf((R[e+1] - mu) * rstd, lng[e+1], lnb[e+1]);
                u[p] = f2bf(v0) | (f2bf(v1) << 16);
            }
            uint4 pk = make_uint4(u[0], u[1], u[2], u[3]);
            *(uint4*)(dst + eq * 8) = pk;
        }
    }
}

// ---------------- K2: MFMA GEMM  f_proj[pos][o] = fws[pos][:] @ pw + pb
// B staged once (32KB, XOR-swizzled); A fragments loaded straight from global
// (contiguous 16B per lane in pos-major fws). 256-row M-tile per block.
__global__ __launch_bounds__(256, 4) void k_gemm(
    const unsigned short* __restrict__ fws, const float* __restrict__ pw,
    const float* __restrict__ pb, float* __restrict__ f_proj,
    int M_len, int pos_off)
{
    __shared__ __align__(16) char Bsh[64 * 256 * 2];   // [o64][k256] bf16, XOR-swizzled
    const int tid = threadIdx.x;
    const int l   = tid & 63;
    const int w   = tid >> 6;
    const int m0  = blockIdx.x * 256;

    // stage B: pw is [k256][o64] fp32 -> Bsh[o][k] bf16
    for (int idx = tid; idx < 16384; idx += 256) {
        int k = idx >> 6, o = idx & 63;
        unsigned u = f2bf(pw[idx]);
        int dstoff = (o * 512 + k * 2) ^ ((o & 7) << 4);
        *(unsigned short*)(Bsh + dstoff) = (unsigned short)u;
    }
    __syncthreads();

    f32x4 acc[4][4];
    #pragma unroll
    for (int mi = 0; mi < 4; ++mi)
        #pragma unroll
        for (int nt = 0; nt < 4; ++nt) acc[mi][nt] = (f32x4)(0.f);

    #pragma unroll
    for (int mi = 0; mi < 4; ++mi) {
        int row = m0 + w * 64 + mi * 16 + (l & 15);
        int rowc = row < M_len ? row : (M_len - 1);
        const unsigned short* abase = fws + (size_t)rowc * 256 + ((l >> 4) << 3);
        #pragma unroll
        for (int ks = 0; ks < 8; ++ks) {
            bf16x8 a = *(const bf16x8*)(abase + ks * 32);
            #pragma unroll
            for (int nt = 0; nt < 4; ++nt) {
                int o = nt * 16 + (l & 15);
                int boff = (o * 512 + ks * 64 + ((l >> 4) << 4)) ^ ((o & 7) << 4);
                bf16x8 bb = *(const bf16x8*)(Bsh + boff);
                acc[mi][nt] = __builtin_amdgcn_mfma_f32_16x16x32_bf16(a, bb, acc[mi][nt], 0, 0, 0);
            }
        }
    }

    #pragma unroll
    for (int mi = 0; mi < 4; ++mi)
        #pragma unroll
        for (int nt = 0; nt < 4; ++nt) {
            int col = nt * 16 + (l & 15);
            float bias = pb[col];
            #pragma unroll
            for (int r = 0; r < 4; ++r) {
                int row = m0 + w * 64 + mi * 16 + (l >> 4) * 4 + r;
                if (row < M_len)
                    f_proj[(size_t)(pos_off + row) * 64 + col] = acc[mi][nt][r] + bias;
            }
        }
}

// ---------------- fallback (R2-proven): full fused kernel writing f_proj
__global__ __launch_bounds__(256, 3) void k_expm_fb(
    const float* __restrict__ x, const float* __restrict__ mask,
    const float* __restrict__ Wd, const float* __restrict__ lng,
    const float* __restrict__ lnb, const float* __restrict__ pw,
    const float* __restrict__ pb, float* __restrict__ f_out)
{
    __shared__ __align__(16) unsigned char smA[256 * 64 * 2];
    __shared__ __align__(16) float pwsh[64 * 64];
    float* xT = (float*)smA;
    unsigned short* fsh = (unsigned short*)smA;

    const int tid  = threadIdx.x;
    const int lane = tid & 63;
    const int wq   = __builtin_amdgcn_readfirstlane(tid >> 6);
    const int b    = blockIdx.x >> 5;
    const int t0   = (blockIdx.x & 31) << 6;

    const float* xb = x + (size_t)b * (T_ * D_);
    for (int idx = tid; idx < 65 * 64; idx += 256) {
        int r = idx >> 6, c = idx & 63;
        int tr = t0 + r;
        xT[c * 65 + r] = (tr < T_) ? xb[tr * 64 + c] : 0.f;
    }
    __syncthreads();

    const int t = t0 + lane;
    const bool valid = (t < TM1);
    const float mk = valid ? mask[b * T_ + t + 1] : 0.f;

    float al[28];
    #pragma unroll
    for (int p = 0; p < 28; ++p) al[p] = 0.f;
    const float* Wg = Wd + wq * (16 * 64);
    #pragma unroll
    for (int d = 0; d < 16; ++d) {
        const float* col = &xT[(wq * 16 + d) * 65 + lane];
        float dxd = (col[1] - col[0]) * mk;
        const float* Wrow = Wg + d * 64;
        #pragma unroll
        for (int i = 1; i < 8; ++i)
            #pragma unroll
            for (int j = 0; j < i; ++j)
                al[PID(i, j)] = fmaf(dxd, Wrow[i * 8 + j], al[PID(i, j)]);
    }
    __syncthreads();

    #pragma unroll
    for (int p = 0; p < 28; ++p) al[p] *= 0.125f;

    float R[64];
    #pragma unroll
    for (int i = 0; i < 8; ++i)
        #pragma unroll
        for (int j = 0; j < 8; ++j)
            R[i * 8 + j] = (i == j) ? 1.f : 0.f;
    for (int k = 9; k >= 1; --k) {
        float invk = 1.f / (float)k;
        #pragma unroll
        for (int j = 0; j < 8; ++j) {
            float tmp[8];
            #pragma unroll
            for (int i = 0; i < 8; ++i) tmp[i] = R[i * 8 + j];
            #pragma unroll
            for (int i = 0; i < 8; ++i) {
                float s = 0.f;
                #pragma unroll
                for (int kk = 0; kk < 8; ++kk) {
                    if (kk == i) continue;
                    float a = (i > kk) ? al[PID(i, kk)] : -al[PID(kk, i)];
                    s = fmaf(a, tmp[kk], s);
                }
                R[i * 8 + j] = ((i == j) ? 1.f : 0.f) + invk * s;
            }
        }
    }
    for (int sq = 0; sq < 3; ++sq) {
        float nw[64];
        #pragma unroll
        for (int i = 0; i < 8; ++i)
            #pragma unroll
            for (int j = 0; j < 8; ++j) {
                float s = 0.f;
                #pragma unroll
                for (int kk = 0; kk < 8; ++kk)
                    s = fmaf(R[i * 8 + kk], R[kk * 8 + j], s);
                nw[i * 8 + j] = s;
            }
        #pragma unroll
        for (int e = 0; e < 64; ++e) R[e] = nw[e];
    }

    float sum = 0.f, ssq = 0.f;
    #pragma unroll
    for (int e = 0; e < 64; ++e) { sum += R[e]; ssq = fmaf(R[e], R[e], ssq); }
    float mu   = sum * (1.f / 64.f);
    float var  = ssq * (1.f / 64.f) - mu * mu;
    float rstd = rsqrtf(var + 1e-5f);

    #pragma unroll
    for (int e = 0; e < 64; ++e) {
        float nv = fmaf((R[e] - mu) * rstd, lng[e], lnb[e]);
        fsh[(wq * 64 + e) * 64 + lane] = (unsigned short)f2bf(nv);
    }

    float acc[16];
    #pragma unroll
    for (int j = 0; j < 16; ++j) acc[j] = 0.f;
    for (int c = 0; c < 4; ++c) {
        __syncthreads();
        for (int idx = tid; idx < 4096; idx += 256)
            pwsh[idx] = pw[c * 4096 + idx];
        __syncthreads();
        #pragma unroll 4
        for (int e = 0; e < 64; ++e) {
            float fe = __uint_as_float((unsigned)fsh[(c * 64 + e) * 64 + lane] << 16);
            const float* wr = &pwsh[e * 64 + wq * 16];
            #pragma unroll
            for (int j = 0; j < 16; ++j)
                acc[j] = fmaf(fe, wr[j], acc[j]);
        }
    }
    if (valid) {
        float* dst = f_out + ((size_t)b * TM1 + t) * 64 + wq * 16;
        #pragma unroll
        for (int j = 0; j < 16; ++j) dst[j] = acc[j] + pb[wq * 16 + j];
    }
}

// ---------------- K3: pooled / denom
__global__ void k_pool(const float* __restrict__ x, const float* __restrict__ mask,
                       const float* __restrict__ f, float* __restrict__ pooled,
                       float* __restrict__ denom)
{
    const int b  = blockIdx.x >> 5;
    const int t0 = (blockIdx.x & 31) << 6;
    const int o  = threadIdx.x & 63;
    const int tr = threadIdx.x >> 6;
    const float* xb = x + (size_t)b * (T_ * D_);
    const float* fb = f + (size_t)b * (TM1 * 64);
    float acc = 0.f, am = 0.f;
    #pragma unroll 4
    for (int i = 0; i < 16; ++i) {
        int tt = t0 + i * 4 + tr;
        float mk  = mask[b * T_ + tt];
        float pos = fminf(fmaxf((tt + 0.5f) * (2047.f / 2048.f) - 0.5f, 0.f), 2046.f);
        int   i0  = (int)pos;
        float w   = pos - (float)i0;
        int   i1  = min(i0 + 1, 2046);
        float fi  = fb[i0 * 64 + o] * (1.f - w) + fb[i1 * 64 + o] * w;
        float h1  = xb[tt * 64 + o] + fi;
        acc = fmaf(h1, mk, acc);
        am += mk;
    }
    atomicAdd(&pooled[b * 64 + o], acc);
    if (o == 0) atomicAdd(&denom[b], am);
}

// ---------------- K4: SE gate
__global__ void k_se(const float* __restrict__ pooled, const float* __restrict__ denom,
                     const float* __restrict__ w1, const float* __restrict__ b1,
                     const float* __restrict__ w2, const float* __restrict__ b2,
                     float* __restrict__ s_out)
{
    __shared__ float pl[64];
    __shared__ float hid[4];
    const int b = blockIdx.x, o = threadIdx.x;
    float p = pooled[b * 64 + o] / denom[b];
    pl[o] = p;
    __syncthreads();
    if (o < 4) {
        float h = b1[o];
        for (int e = 0; e < 64; ++e) h = fmaf(pl[e], w1[e * 4 + o], h);
        hid[o] = 0.5f * h * (1.f + erff(h * 0.70710678118654752f));
    }
    __syncthreads();
    float sv = b2[o];
    #pragma unroll
    for (int hh = 0; hh < 4; ++hh) sv = fmaf(hid[hh], w2[hh * 64 + o], sv);
    s_out[b * 64 + o] = 1.f / (1.f + expf(-sv));
}

// ---------------- K5: out = (x + interp(f)) * s + x
__global__ void k_apply(const float* __restrict__ x, const float* __restrict__ f,
                        const float* __restrict__ s, float* __restrict__ out)
{
    int gid = blockIdx.x * 256 + threadIdx.x;
    int o = gid & 63;
    int t = (gid >> 6) & 2047;
    int b = gid >> 17;
    float pos = fminf(fmaxf((t + 0.5f) * (2047.f / 2048.f) - 0.5f, 0.f), 2046.f);
    int   i0  = (int)pos;
    float w   = pos - (float)i0;
    int   i1  = min(i0 + 1, 2046);
    const float* fb = f + (size_t)b * (TM1 * 64);
    float fi = fb[i0 * 64 + o] * (1.f - w) + fb[i1 * 64 + o] * w;
    float xv = x[gid];
    float h1 = xv + fi;
    out[gid] = fmaf(h1, s[b * 64 + o], xv);
}

extern "C" void kernel_launch(void* const* d_in, const int* in_sizes, int n_in,
                              void* d_out, int out_size, void* d_ws, size_t ws_size,
                              hipStream_t stream)
{
    const float* x    = (const float*)d_in[0];
    const float* mask = (const float*)d_in[1];
    const float* Wd   = (const float*)d_in[2];
    const float* lng  = (const float*)d_in[3];
    const float* lnb  = (const float*)d_in[4];
    const float* pw   = (const float*)d_in[5];
    const float* pb   = (const float*)d_in[6];
    const float* sw1  = (const float*)d_in[7];
    const float* sb1  = (const float*)d_in[8];
    const float* sw2  = (const float*)d_in[9];
    const float* sb2  = (const float*)d_in[10];

    float* out    = (float*)d_out;
    float* pooled = (float*)d_ws;                   // 4096
    float* denom  = pooled + 4096;                  // 64
    float* s_ws   = denom + 64;                     // 4096
    float* f_proj = s_ws + 4096;                    // 8,384,512 floats (33.5 MB)
    unsigned short* fws = (unsigned short*)(f_proj + (size_t)M_FULL * 64);

    const size_t base_bytes = (size_t)(4096 + 64 + 4096 + (size_t)M_FULL * 64) * 4;
    const size_t need_full  = base_bytes + (size_t)M_FULL * 256 * 2;         // +67.1 MB
    const size_t need_half  = base_bytes + (size_t)(M_FULL / 2) * 256 * 2;   // +33.5 MB

    hipMemsetAsync(pooled, 0, (4096 + 64) * sizeof(float), stream);

    if (ws_size >= need_full) {
        hipLaunchKernelGGL(k_expm_f, dim3(2048), dim3(256), 0, stream,
                           x, mask, Wd, lng, lnb, fws, 0);
        hipLaunchKernelGGL(k_gemm, dim3((M_FULL + 255) / 256), dim3(256), 0, stream,
                           fws, pw, pb, f_proj, M_FULL, 0);
    } else if (ws_size >= need_half) {
        const int Mh = M_FULL / 2;                  // 65504 = 32*2047
        hipLaunchKernelGGL(k_expm_f, dim3(1024), dim3(256), 0, stream,
                           x, mask, Wd, lng, lnb, fws, 0);
        hipLaunchKernelGGL(k_gemm, dim3((Mh + 255) / 256), dim3(256), 0, stream,
                           fws, pw, pb, f_proj, Mh, 0);
        hipLaunchKernelGGL(k_expm_f, dim3(1024), dim3(256), 0, stream,
                           x, mask, Wd, lng, lnb, fws, 32);
        hipLaunchKernelGGL(k_gemm, dim3((Mh + 255) / 256), dim3(256), 0, stream,
                           fws, pw, pb, f_proj, Mh, Mh);
    } else {
        hipLaunchKernelGGL(k_expm_fb, dim3(2048), dim3(256), 0, stream,
                           x, mask, Wd, lng, lnb, pw, pb, f_proj);
    }

    hipLaunchKernelGGL(k_pool, dim3(2048), dim3(256), 0, stream,
                       x, mask, f_proj, pooled, denom);
    hipLaunchKernelGGL(k_se, dim3(64), dim3(64), 0, stream,
                       pooled, denom, sw1, sb1, sw2, sb2, s_ws);
    hipLaunchKernelGGL(k_apply, dim3(32768), dim3(256), 0, stream,
                       x, f_proj, s_ws, out);

    hipMemcpyAsync(out + (size_t)B_ * T_ * D_, mask,
                   (size_t)B_ * T_ * sizeof(float), hipMemcpyDeviceToDevice, stream);
}

// Round 6
// 281.017 us; speedup vs baseline: 1.8902x; 1.1119x over previous
//
#include <hip/hip_runtime.h>

#define B_   64
#define T_   2048
#define TM1  2047
#define D_   64

#define PID(i,j) ((i)*((i)-1)/2 + (j))

typedef __attribute__((ext_vector_type(8))) short bf16x8;
typedef __attribute__((ext_vector_type(4))) float f32x4;

__device__ __forceinline__ unsigned f2bf(float v) {
    unsigned u = __float_as_uint(v);
    u = (u + 0x7FFFu + ((u >> 16) & 1u)) >> 16;   // RNE
    return u;
}
__device__ __forceinline__ float bf2f(unsigned s) {
    return __uint_as_float(s << 16);
}

// ---------------- K0: pack proj_w into per-lane B-fragment layout (bf16, 32KB)
// pwB[((nt*8+ks)*64 + l)*8 + j] = bf16(pw[(ks*32+(l>>4)*8+j)*64 + nt*16+(l&15)])
__global__ void k_prep(const float* __restrict__ pw, unsigned short* __restrict__ pwB)
{
    int idx = blockIdx.x * 256 + threadIdx.x;     // 16384 total
    int j  = idx & 7;
    int l  = (idx >> 3) & 63;
    int ks = (idx >> 9) & 7;
    int nt = idx >> 12;
    int k  = ks * 32 + ((l >> 4) << 3) + j;
    int o  = nt * 16 + (l & 15);
    pwB[idx] = (unsigned short)f2bf(pw[k * 64 + o]);
}

// ---------------- K1: dX -> Mlie -> expm(s=4, Horner-6) -> LN -> MFMA proj -> f bf16 + pooled_f
// (256,3): proven spill-free regime (R2); (256,4) scratch-spills ~1GB (R3).
__global__ __launch_bounds__(256, 3) void k_expm_f2(
    const float* __restrict__ x, const float* __restrict__ mask,
    const float* __restrict__ Wd, const float* __restrict__ lng,
    const float* __restrict__ lnb, const unsigned short* __restrict__ pwB,
    const float* __restrict__ pb, unsigned short* __restrict__ fbf,
    float* __restrict__ pooled)
{
    __shared__ __align__(16) unsigned char smem[32768];
    float* xT = (float*)smem;                       // phase 1: 64x65 f32 (16.6KB)

    const int tid  = threadIdx.x;
    const int lane = tid & 63;
    const int wq   = __builtin_amdgcn_readfirstlane(tid >> 6);
    const int bl   = blockIdx.x >> 5;
    const int t0   = (blockIdx.x & 31) << 6;

    const float* xb = x + (size_t)bl * (T_ * D_);
    for (int idx = tid; idx < 65 * 64; idx += 256) {
        int r = idx >> 6, c = idx & 63;
        int tr = t0 + r;
        xT[c * 65 + r] = (tr < T_) ? xb[tr * 64 + c] : 0.f;
    }
    __syncthreads();

    const int t = t0 + lane;
    const bool valid = (t < TM1);
    const float* mrow = mask + bl * T_;
    const float mk = valid ? mrow[t + 1] : 0.f;

    float al[28];
    #pragma unroll
    for (int p = 0; p < 28; ++p) al[p] = 0.f;
    const float* Wg = Wd + wq * (16 * 64);
    #pragma unroll
    for (int d = 0; d < 16; ++d) {
        const float* col = &xT[(wq * 16 + d) * 65 + lane];
        float dxd = (col[1] - col[0]) * mk;
        const float* Wrow = Wg + d * 64;
        #pragma unroll
        for (int i = 1; i < 8; ++i)
            #pragma unroll
            for (int j = 0; j < i; ++j)
                al[PID(i, j)] = fmaf(dxd, Wrow[i * 8 + j], al[PID(i, j)]);
    }
    __syncthreads();                                // xT dead; smem reused for f staging

    #pragma unroll
    for (int p = 0; p < 28; ++p) al[p] *= 0.0625f;  // 1/2^4

    // Horner Taylor-6, in-place column update
    float R[64];
    #pragma unroll
    for (int i = 0; i < 8; ++i)
        #pragma unroll
        for (int j = 0; j < 8; ++j)
            R[i * 8 + j] = (i == j) ? 1.f : 0.f;
    for (int k = 6; k >= 1; --k) {
        float invk = 1.f / (float)k;
        #pragma unroll
        for (int j = 0; j < 8; ++j) {
            float tmp[8];
            #pragma unroll
            for (int i = 0; i < 8; ++i) tmp[i] = R[i * 8 + j];
            #pragma unroll
            for (int i = 0; i < 8; ++i) {
                float s = 0.f;
                #pragma unroll
                for (int kk = 0; kk < 8; ++kk) {
                    if (kk == i) continue;
                    float a = (i > kk) ? al[PID(i, kk)] : -al[PID(kk, i)];
                    s = fmaf(a, tmp[kk], s);
                }
                R[i * 8 + j] = ((i == j) ? 1.f : 0.f) + invk * s;
            }
        }
    }
    for (int sq = 0; sq < 4; ++sq) {
        float nw[64];
        #pragma unroll
        for (int i = 0; i < 8; ++i)
            #pragma unroll
            for (int j = 0; j < 8; ++j) {
                float s = 0.f;
                #pragma unroll
                for (int kk = 0; kk < 8; ++kk)
                    s = fmaf(R[i * 8 + kk], R[kk * 8 + j], s);
                nw[i * 8 + j] = s;
            }
        #pragma unroll
        for (int e = 0; e < 64; ++e) R[e] = nw[e];
    }

    float sum = 0.f, ssq = 0.f;
    #pragma unroll
    for (int e = 0; e < 64; ++e) { sum += R[e]; ssq = fmaf(R[e], R[e], ssq); }
    float mu   = sum * (1.f / 64.f);
    float var  = ssq * (1.f / 64.f) - mu * mu;
    float rstd = rsqrtf(var + 1e-5f);

    // stage LN'd f as bf16 into LDS: row=lane (t-local, 512B), 8B slots XOR-swizzled
    #pragma unroll
    for (int eq = 0; eq < 16; ++eq) {
        int e = eq * 4;
        float v0 = fmaf((R[e]   - mu) * rstd, lng[e],   lnb[e]);
        float v1 = fmaf((R[e+1] - mu) * rstd, lng[e+1], lnb[e+1]);
        float v2 = fmaf((R[e+2] - mu) * rstd, lng[e+2], lnb[e+2]);
        float v3 = fmaf((R[e+3] - mu) * rstd, lng[e+3], lnb[e+3]);
        uint2 pk = make_uint2(f2bf(v0) | (f2bf(v1) << 16), f2bf(v2) | (f2bf(v3) << 16));
        int slot = wq * 16 + eq;
        int sw = slot ^ ((lane & 7) << 1);
        *(uint2*)(smem + lane * 512 + sw * 8) = pk;
    }
    __syncthreads();

    // MFMA proj: wave wq owns rows wq*16..+16; K=256 over 8 ks steps
    f32x4 acc[4];
    #pragma unroll
    for (int nt = 0; nt < 4; ++nt) acc[nt] = (f32x4)(0.f);
    const int arow = wq * 16 + (lane & 15);
    #pragma unroll
    for (int ks = 0; ks < 8; ++ks) {
        int c = ks * 4 + (lane >> 4);
        bf16x8 a = *(const bf16x8*)(smem + arow * 512 + (c ^ (arow & 7)) * 16);
        #pragma unroll
        for (int nt = 0; nt < 4; ++nt) {
            bf16x8 bb = *(const bf16x8*)(pwB + (((nt * 8 + ks) * 64 + lane) << 3));
            acc[nt] = __builtin_amdgcn_mfma_f32_16x16x32_bf16(a, bb, acc[nt], 0, 0, 0);
        }
    }
    __syncthreads();                                // all A-frag reads done

    // epilogue: bias, pooled_f (interp-adjoint gamma), restage output in LDS
    unsigned short* fosh = (unsigned short*)smem;   // 64 rows x 64 cols bf16 (8KB)
    float bias[4];
    #pragma unroll
    for (int nt = 0; nt < 4; ++nt) bias[nt] = pb[nt * 16 + (lane & 15)];
    float pf[4] = {0.f, 0.f, 0.f, 0.f};
    #pragma unroll
    for (int r = 0; r < 4; ++r) {
        int pl = wq * 16 + ((lane >> 4) << 2) + r;  // local row
        int p  = t0 + pl;
        float g = 0.f;
        if (p < TM1) {
            float mp  = mrow[p];
            float mp1 = mrow[p + 1];
            float wlo = (p + 1.5f) * (1.f / 2048.f);
            float whi = 1.f - (p + 0.5f) * (1.f / 2048.f);
            if (p == 0)          g = mp + mp1 * wlo;
            else if (p == 2046)  g = mp * whi + mp1;
            else                 g = mp * whi + mp1 * wlo;
        }
        #pragma unroll
        for (int nt = 0; nt < 4; ++nt) {
            float fv = acc[nt][r] + bias[nt];
            pf[nt] = fmaf(g, fv, pf[nt]);
            fosh[pl * 64 + nt * 16 + (lane & 15)] = (unsigned short)f2bf(fv);
        }
    }
    #pragma unroll
    for (int nt = 0; nt < 4; ++nt) {
        pf[nt] += __shfl_xor(pf[nt], 16);
        pf[nt] += __shfl_xor(pf[nt], 32);
    }
    if (lane < 16) {
        #pragma unroll
        for (int nt = 0; nt < 4; ++nt)
            atomicAdd(&pooled[bl * 64 + nt * 16 + lane], pf[nt]);
    }
    __syncthreads();

    // coalesced bf16 output: 512 chunks of 16B
    #pragma unroll
    for (int i = 0; i < 2; ++i) {
        int C = i * 256 + tid;
        int row = C >> 3, c = C & 7;
        int p = t0 + row;
        if (p < TM1) {
            uint4 vv = *(const uint4*)(smem + C * 16);
            *(uint4*)(fbf + ((size_t)bl * TM1 + p) * 64 + c * 8) = vv;
        }
    }
}

// ---------------- K2: pooled += sum_t mask*x ; denom
__global__ void k_poolx(const float* __restrict__ x, const float* __restrict__ mask,
                        float* __restrict__ pooled, float* __restrict__ denom)
{
    const int b  = blockIdx.x >> 5;
    const int t0 = (blockIdx.x & 31) << 6;
    const int o  = threadIdx.x & 63;
    const int tr = threadIdx.x >> 6;
    const float* xb = x + (size_t)b * (T_ * D_);
    float acc = 0.f, am = 0.f;
    #pragma unroll 4
    for (int i = 0; i < 16; ++i) {
        int tt = t0 + i * 4 + tr;
        float mkv = mask[b * T_ + tt];
        acc = fmaf(xb[tt * 64 + o], mkv, acc);
        am += mkv;
    }
    atomicAdd(&pooled[b * 64 + o], acc);
    if (o == 0) atomicAdd(&denom[b], am);
}

// ---------------- K3: SE gate
__global__ void k_se(const float* __restrict__ pooled, const float* __restrict__ denom,
                     const float* __restrict__ w1, const float* __restrict__ b1,
                     const float* __restrict__ w2, const float* __restrict__ b2,
                     float* __restrict__ s_out)
{
    __shared__ float pl[64];
    __shared__ float hid[4];
    const int b = blockIdx.x, o = threadIdx.x;
    float p = pooled[b * 64 + o] / denom[b];
    pl[o] = p;
    __syncthreads();
    if (o < 4) {
        float h = b1[o];
        for (int e = 0; e < 64; ++e) h = fmaf(pl[e], w1[e * 4 + o], h);
        hid[o] = 0.5f * h * (1.f + erff(h * 0.70710678118654752f));
    }
    __syncthreads();
    float sv = b2[o];
    #pragma unroll
    for (int hh = 0; hh < 4; ++hh) sv = fmaf(hid[hh], w2[hh * 64 + o], sv);
    s_out[b * 64 + o] = 1.f / (1.f + expf(-sv));
}

// ---------------- K4: out = (x + interp(f)) * s + x   (f is bf16, 4 outputs/thread)
__global__ void k_apply(const float* __restrict__ x, const unsigned short* __restrict__ fbf,
                        const float* __restrict__ s, float* __restrict__ out)
{
    int gid = blockIdx.x * 256 + threadIdx.x;       // 2,097,152 groups of 4
    int o4 = (gid & 15) << 2;
    int t  = (gid >> 4) & 2047;
    int b  = gid >> 15;
    float pos = fminf(fmaxf((t + 0.5f) * (2047.f / 2048.f) - 0.5f, 0.f), 2046.f);
    int   i0  = (int)pos;
    float w   = pos - (float)i0;
    int   i1  = min(i0 + 1, 2046);
    const unsigned short* fb = fbf + (size_t)b * (TM1 * 64);
    uint2 u0 = *(const uint2*)(fb + i0 * 64 + o4);
    uint2 u1 = *(const uint2*)(fb + i1 * 64 + o4);
    size_t base = ((size_t)b * T_ + t) * 64 + o4;
    float4 xv = *(const float4*)(x + base);
    float4 sv = *(const float4*)(s + b * 64 + o4);
    float4 ov;
    float f00 = bf2f(u0.x & 0xffffu), f01 = bf2f(u0.x >> 16);
    float f02 = bf2f(u0.y & 0xffffu), f03 = bf2f(u0.y >> 16);
    float f10 = bf2f(u1.x & 0xffffu), f11 = bf2f(u1.x >> 16);
    float f12 = bf2f(u1.y & 0xffffu), f13 = bf2f(u1.y >> 16);
    ov.x = fmaf(xv.x + f00 * (1.f - w) + f10 * w, sv.x, xv.x);
    ov.y = fmaf(xv.y + f01 * (1.f - w) + f11 * w, sv.y, xv.y);
    ov.z = fmaf(xv.z + f02 * (1.f - w) + f12 * w, sv.z, xv.z);
    ov.w = fmaf(xv.w + f03 * (1.f - w) + f13 * w, sv.w, xv.w);
    *(float4*)(out + base) = ov;
}

extern "C" void kernel_launch(void* const* d_in, const int* in_sizes, int n_in,
                              void* d_out, int out_size, void* d_ws, size_t ws_size,
                              hipStream_t stream)
{
    const float* x    = (const float*)d_in[0];
    const float* mask = (const float*)d_in[1];
    const float* Wd   = (const float*)d_in[2];
    const float* lng  = (const float*)d_in[3];
    const float* lnb  = (const float*)d_in[4];
    const float* pw   = (const float*)d_in[5];
    const float* pb   = (const float*)d_in[6];
    const float* sw1  = (const float*)d_in[7];
    const float* sb1  = (const float*)d_in[8];
    const float* sw2  = (const float*)d_in[9];
    const float* sb2  = (const float*)d_in[10];

    float* out    = (float*)d_out;
    float* pooled = (float*)d_ws;                        // 4096
    float* denom  = pooled + 4096;                       // 64
    float* s_ws   = denom + 64;                          // 4096
    unsigned short* pwB = (unsigned short*)(s_ws + 4096); // 16384 shorts (32KB)
    unsigned short* fbf = pwB + 16384;                   // B*TM1*64 shorts (16.8MB)

    hipMemsetAsync(pooled, 0, (4096 + 64) * sizeof(float), stream);

    hipLaunchKernelGGL(k_prep, dim3(64), dim3(256), 0, stream, pw, pwB);
    hipLaunchKernelGGL(k_expm_f2, dim3(2048), dim3(256), 0, stream,
                       x, mask, Wd, lng, lnb, pwB, pb, fbf, pooled);
    hipLaunchKernelGGL(k_poolx, dim3(2048), dim3(256), 0, stream,
                       x, mask, pooled, denom);
    hipLaunchKernelGGL(k_se, dim3(64), dim3(64), 0, stream,
                       pooled, denom, sw1, sb1, sw2, sb2, s_ws);
    hipLaunchKernelGGL(k_apply, dim3(8192), dim3(256), 0, stream,
                       x, fbf, s_ws, out);

    hipMemcpyAsync(out + (size_t)B_ * T_ * D_, mask,
                   (size_t)B_ * T_ * sizeof(float), hipMemcpyDeviceToDevice, stream);
}

// Round 7
// 222.289 us; speedup vs baseline: 2.3896x; 1.2642x over previous
//
#include <hip/hip_runtime.h>

#define B_   64
#define T_   2048
#define TM1  2047
#define D_   64

#define PID(i,j) ((i)*((i)-1)/2 + (j))

typedef __attribute__((ext_vector_type(8))) short bf16x8;
typedef __attribute__((ext_vector_type(4))) float f32x4;

__device__ __forceinline__ unsigned f2bf(float v) {
    unsigned u = __float_as_uint(v);
    u = (u + 0x7FFFu + ((u >> 16) & 1u)) >> 16;   // RNE
    return u;
}
__device__ __forceinline__ float bf2f(unsigned s) {
    return __uint_as_float(s << 16);
}

// ---------------- K0: pack proj_w into per-lane B-fragment layout (bf16, 32KB)
__global__ void k_prep(const float* __restrict__ pw, unsigned short* __restrict__ pwB)
{
    int idx = blockIdx.x * 256 + threadIdx.x;     // 16384 total
    int j  = idx & 7;
    int l  = (idx >> 3) & 63;
    int ks = (idx >> 9) & 7;
    int nt = idx >> 12;
    int k  = ks * 32 + ((l >> 4) << 3) + j;
    int o  = nt * 16 + (l & 15);
    pwB[idx] = (unsigned short)f2bf(pw[k * 64 + o]);
}

// ---------------- K1: x-pool + dX -> Mlie -> expm(s=4, Horner-6) -> LN -> MFMA proj
//                     -> f bf16 + pooled_f (interp-adjoint) ; denom
// (256,3): proven spill-free regime (R2); (256,4) scratch-spills ~1GB (R3).
__global__ __launch_bounds__(256, 3) void k_expm_f2(
    const float* __restrict__ x, const float* __restrict__ mask,
    const float* __restrict__ Wd, const float* __restrict__ lng,
    const float* __restrict__ lnb, const unsigned short* __restrict__ pwB,
    const float* __restrict__ pb, unsigned short* __restrict__ fbf,
    float* __restrict__ pooled, float* __restrict__ denom)
{
    __shared__ __align__(16) unsigned char smem[32768];
    float* xT = (float*)smem;                       // phase 1: 64x65 f32 (16.6KB)

    const int tid  = threadIdx.x;
    const int lane = tid & 63;
    const int wq   = __builtin_amdgcn_readfirstlane(tid >> 6);
    const int bl   = blockIdx.x >> 5;
    const int t0   = (blockIdx.x & 31) << 6;

    const float* xb = x + (size_t)bl * (T_ * D_);
    for (int idx = tid; idx < 65 * 64; idx += 256) {
        int r = idx >> 6, c = idx & 63;
        int tr = t0 + r;
        xT[c * 65 + r] = (tr < T_) ? xb[tr * 64 + c] : 0.f;
    }
    __syncthreads();

    const int t = t0 + lane;
    const bool valid = (t < TM1);
    const float* mrow = mask + bl * T_;
    const float mk = valid ? mrow[t + 1] : 0.f;

    // ---- fused masked x-pooling (xT live; rows t0..t0+63 belong to this block)
    {
        const int c  = tid & 63;
        const int rg = tid >> 6;                    // 4 row-groups of 16
        float psum = 0.f;
        #pragma unroll
        for (int i = 0; i < 16; ++i) {
            int r = rg * 16 + i;
            psum = fmaf(xT[c * 65 + r], mrow[t0 + r], psum);
        }
        atomicAdd(&pooled[bl * 64 + c], psum);
        if (wq == 0) {
            float dv = mrow[t0 + lane];
            #pragma unroll
            for (int off = 32; off >= 1; off >>= 1) dv += __shfl_xor(dv, off);
            if (lane == 0) atomicAdd(&denom[bl], dv);
        }
    }

    float al[28];
    #pragma unroll
    for (int p = 0; p < 28; ++p) al[p] = 0.f;
    const float* Wg = Wd + wq * (16 * 64);
    #pragma unroll
    for (int d = 0; d < 16; ++d) {
        const float* col = &xT[(wq * 16 + d) * 65 + lane];
        float dxd = (col[1] - col[0]) * mk;
        const float* Wrow = Wg + d * 64;
        #pragma unroll
        for (int i = 1; i < 8; ++i)
            #pragma unroll
            for (int j = 0; j < i; ++j)
                al[PID(i, j)] = fmaf(dxd, Wrow[i * 8 + j], al[PID(i, j)]);
    }
    __syncthreads();                                // xT dead; smem reused for f staging

    #pragma unroll
    for (int p = 0; p < 28; ++p) al[p] *= 0.0625f;  // 1/2^4

    // Horner Taylor-6, in-place column update
    float R[64];
    #pragma unroll
    for (int i = 0; i < 8; ++i)
        #pragma unroll
        for (int j = 0; j < 8; ++j)
            R[i * 8 + j] = (i == j) ? 1.f : 0.f;
    for (int k = 6; k >= 1; --k) {
        float invk = 1.f / (float)k;
        #pragma unroll
        for (int j = 0; j < 8; ++j) {
            float tmp[8];
            #pragma unroll
            for (int i = 0; i < 8; ++i) tmp[i] = R[i * 8 + j];
            #pragma unroll
            for (int i = 0; i < 8; ++i) {
                float s = 0.f;
                #pragma unroll
                for (int kk = 0; kk < 8; ++kk) {
                    if (kk == i) continue;
                    float a = (i > kk) ? al[PID(i, kk)] : -al[PID(kk, i)];
                    s = fmaf(a, tmp[kk], s);
                }
                R[i * 8 + j] = ((i == j) ? 1.f : 0.f) + invk * s;
            }
        }
    }
    for (int sq = 0; sq < 4; ++sq) {
        float nw[64];
        #pragma unroll
        for (int i = 0; i < 8; ++i)
            #pragma unroll
            for (int j = 0; j < 8; ++j) {
                float s = 0.f;
                #pragma unroll
                for (int kk = 0; kk < 8; ++kk)
                    s = fmaf(R[i * 8 + kk], R[kk * 8 + j], s);
                nw[i * 8 + j] = s;
            }
        #pragma unroll
        for (int e = 0; e < 64; ++e) R[e] = nw[e];
    }

    float sum = 0.f, ssq = 0.f;
    #pragma unroll
    for (int e = 0; e < 64; ++e) { sum += R[e]; ssq = fmaf(R[e], R[e], ssq); }
    float mu   = sum * (1.f / 64.f);
    float var  = ssq * (1.f / 64.f) - mu * mu;
    float rstd = rsqrtf(var + 1e-5f);

    // stage LN'd f as bf16 into LDS: row=lane (512B), 8B slots XOR-swizzled
    #pragma unroll
    for (int eq = 0; eq < 16; ++eq) {
        int e = eq * 4;
        float v0 = fmaf((R[e]   - mu) * rstd, lng[e],   lnb[e]);
        float v1 = fmaf((R[e+1] - mu) * rstd, lng[e+1], lnb[e+1]);
        float v2 = fmaf((R[e+2] - mu) * rstd, lng[e+2], lnb[e+2]);
        float v3 = fmaf((R[e+3] - mu) * rstd, lng[e+3], lnb[e+3]);
        uint2 pk = make_uint2(f2bf(v0) | (f2bf(v1) << 16), f2bf(v2) | (f2bf(v3) << 16));
        int slot = wq * 16 + eq;
        int sw = slot ^ ((lane & 7) << 1);
        *(uint2*)(smem + lane * 512 + sw * 8) = pk;
    }
    __syncthreads();

    // MFMA proj: wave wq owns rows wq*16..+16; K=256 over 8 ks steps
    f32x4 acc[4];
    #pragma unroll
    for (int nt = 0; nt < 4; ++nt) acc[nt] = (f32x4)(0.f);
    const int arow = wq * 16 + (lane & 15);
    #pragma unroll
    for (int ks = 0; ks < 8; ++ks) {
        int c = ks * 4 + (lane >> 4);
        bf16x8 a = *(const bf16x8*)(smem + arow * 512 + (c ^ (arow & 7)) * 16);
        #pragma unroll
        for (int nt = 0; nt < 4; ++nt) {
            bf16x8 bb = *(const bf16x8*)(pwB + (((nt * 8 + ks) * 64 + lane) << 3));
            acc[nt] = __builtin_amdgcn_mfma_f32_16x16x32_bf16(a, bb, acc[nt], 0, 0, 0);
        }
    }
    __syncthreads();                                // all A-frag reads done

    // epilogue: bias, pooled_f (interp-adjoint gamma), restage output in LDS
    unsigned short* fosh = (unsigned short*)smem;   // 64 rows x 64 cols bf16 (8KB)
    float bias[4];
    #pragma unroll
    for (int nt = 0; nt < 4; ++nt) bias[nt] = pb[nt * 16 + (lane & 15)];
    float pf[4] = {0.f, 0.f, 0.f, 0.f};
    #pragma unroll
    for (int r = 0; r < 4; ++r) {
        int pl = wq * 16 + ((lane >> 4) << 2) + r;  // local row
        int p  = t0 + pl;
        float g = 0.f;
        if (p < TM1) {
            float mp  = mrow[p];
            float mp1 = mrow[p + 1];
            float wlo = (p + 1.5f) * (1.f / 2048.f);
            float whi = 1.f - (p + 0.5f) * (1.f / 2048.f);
            if (p == 0)          g = mp + mp1 * wlo;
            else if (p == 2046)  g = mp * whi + mp1;
            else                 g = mp * whi + mp1 * wlo;
        }
        #pragma unroll
        for (int nt = 0; nt < 4; ++nt) {
            float fv = acc[nt][r] + bias[nt];
            pf[nt] = fmaf(g, fv, pf[nt]);
            fosh[pl * 64 + nt * 16 + (lane & 15)] = (unsigned short)f2bf(fv);
        }
    }
    #pragma unroll
    for (int nt = 0; nt < 4; ++nt) {
        pf[nt] += __shfl_xor(pf[nt], 16);
        pf[nt] += __shfl_xor(pf[nt], 32);
    }
    if (lane < 16) {
        #pragma unroll
        for (int nt = 0; nt < 4; ++nt)
            atomicAdd(&pooled[bl * 64 + nt * 16 + lane], pf[nt]);
    }
    __syncthreads();

    // coalesced bf16 output: 512 chunks of 16B
    #pragma unroll
    for (int i = 0; i < 2; ++i) {
        int C = i * 256 + tid;
        int row = C >> 3, c = C & 7;
        int p = t0 + row;
        if (p < TM1) {
            uint4 vv = *(const uint4*)(smem + C * 16);
            *(uint4*)(fbf + ((size_t)bl * TM1 + p) * 64 + c * 8) = vv;
        }
    }
}

// ---------------- K3: SE gate
__global__ void k_se(const float* __restrict__ pooled, const float* __restrict__ denom,
                     const float* __restrict__ w1, const float* __restrict__ b1,
                     const float* __restrict__ w2, const float* __restrict__ b2,
                     float* __restrict__ s_out)
{
    __shared__ float pl[64];
    __shared__ float hid[4];
    const int b = blockIdx.x, o = threadIdx.x;
    float p = pooled[b * 64 + o] / denom[b];
    pl[o] = p;
    __syncthreads();
    if (o < 4) {
        float h = b1[o];
        for (int e = 0; e < 64; ++e) h = fmaf(pl[e], w1[e * 4 + o], h);
        hid[o] = 0.5f * h * (1.f + erff(h * 0.70710678118654752f));
    }
    __syncthreads();
    float sv = b2[o];
    #pragma unroll
    for (int hh = 0; hh < 4; ++hh) sv = fmaf(hid[hh], w2[hh * 64 + o], sv);
    s_out[b * 64 + o] = 1.f / (1.f + expf(-sv));
}

// ---------------- K4: out = (x + interp(f)) * s + x   (f is bf16, 4 outputs/thread)
__global__ void k_apply(const float* __restrict__ x, const unsigned short* __restrict__ fbf,
                        const float* __restrict__ s, float* __restrict__ out)
{
    int gid = blockIdx.x * 256 + threadIdx.x;
    int o4 = (gid & 15) << 2;
    int t  = (gid >> 4) & 2047;
    int b  = gid >> 15;
    float pos = fminf(fmaxf((t + 0.5f) * (2047.f / 2048.f) - 0.5f, 0.f), 2046.f);
    int   i0  = (int)pos;
    float w   = pos - (float)i0;
    int   i1  = min(i0 + 1, 2046);
    const unsigned short* fb = fbf + (size_t)b * (TM1 * 64);
    uint2 u0 = *(const uint2*)(fb + i0 * 64 + o4);
    uint2 u1 = *(const uint2*)(fb + i1 * 64 + o4);
    size_t base = ((size_t)b * T_ + t) * 64 + o4;
    float4 xv = *(const float4*)(x + base);
    float4 sv = *(const float4*)(s + b * 64 + o4);
    float4 ov;
    float f00 = bf2f(u0.x & 0xffffu), f01 = bf2f(u0.x >> 16);
    float f02 = bf2f(u0.y & 0xffffu), f03 = bf2f(u0.y >> 16);
    float f10 = bf2f(u1.x & 0xffffu), f11 = bf2f(u1.x >> 16);
    float f12 = bf2f(u1.y & 0xffffu), f13 = bf2f(u1.y >> 16);
    ov.x = fmaf(xv.x + f00 * (1.f - w) + f10 * w, sv.x, xv.x);
    ov.y = fmaf(xv.y + f01 * (1.f - w) + f11 * w, sv.y, xv.y);
    ov.z = fmaf(xv.z + f02 * (1.f - w) + f12 * w, sv.z, xv.z);
    ov.w = fmaf(xv.w + f03 * (1.f - w) + f13 * w, sv.w, xv.w);
    *(float4*)(out + base) = ov;
}

extern "C" void kernel_launch(void* const* d_in, const int* in_sizes, int n_in,
                              void* d_out, int out_size, void* d_ws, size_t ws_size,
                              hipStream_t stream)
{
    const float* x    = (const float*)d_in[0];
    const float* mask = (const float*)d_in[1];
    const float* Wd   = (const float*)d_in[2];
    const float* lng  = (const float*)d_in[3];
    const float* lnb  = (const float*)d_in[4];
    const float* pw   = (const float*)d_in[5];
    const float* pb   = (const float*)d_in[6];
    const float* sw1  = (const float*)d_in[7];
    const float* sb1  = (const float*)d_in[8];
    const float* sw2  = (const float*)d_in[9];
    const float* sb2  = (const float*)d_in[10];

    float* out    = (float*)d_out;
    float* pooled = (float*)d_ws;                        // 4096
    float* denom  = pooled + 4096;                       // 64
    float* s_ws   = denom + 64;                          // 4096
    unsigned short* pwB = (unsigned short*)(s_ws + 4096); // 16384 shorts (32KB)
    unsigned short* fbf = pwB + 16384;                   // B*TM1*64 shorts (16.8MB)

    hipMemsetAsync(pooled, 0, (4096 + 64) * sizeof(float), stream);

    hipLaunchKernelGGL(k_prep, dim3(64), dim3(256), 0, stream, pw, pwB);
    hipLaunchKernelGGL(k_expm_f2, dim3(2048), dim3(256), 0, stream,
                       x, mask, Wd, lng, lnb, pwB, pb, fbf, pooled, denom);
    hipLaunchKernelGGL(k_se, dim3(64), dim3(64), 0, stream,
                       pooled, denom, sw1, sb1, sw2, sb2, s_ws);
    hipLaunchKernelGGL(k_apply, dim3(8192), dim3(256), 0, stream,
                       x, fbf, s_ws, out);

    hipMemcpyAsync(out + (size_t)B_ * T_ * D_, mask,
                   (size_t)B_ * T_ * sizeof(float), hipMemcpyDeviceToDevice, stream);
}